// Round 3
// baseline (1114.319 us; speedup 1.0000x reference)
//
#include <hip/hip_runtime.h>

using bf16x8 = __attribute__((ext_vector_type(8))) short;
using f32x4  = __attribute__((ext_vector_type(4))) float;

#define HW   4096
#define CIN  256
#define OFFC 166

// ws element offsets (ushort) for fragment-major bf16 weights per branch
#define WS3_BASE 0
#define WS5_BASE 589824
#define WS7_BASE 2228224
#define WS_TOTAL 5439488   // elems; *2 bytes = 10,878,976 B

__device__ __forceinline__ unsigned short f2bf(float f) {
    unsigned u = __builtin_bit_cast(unsigned, f);
    return (unsigned short)((u + 0x7fffu + ((u >> 16) & 1u)) >> 16);   // RNE
}
__device__ __forceinline__ float bf2f(unsigned v) {
    return __builtin_bit_cast(float, v << 16);
}

// ---------------- weight prep: fp32 [o][c][kh][kw] -> bf16 fragment-major ----------------
// ws[base + ((ks*16 + gm)*64 + lane)*8 + e] = w[o = gm*16 + (lane&15)][c][j]
// with r = ks*32 + (lane>>4)*8 + e,  j = r>>8, c = r&255   (j-major K flattening)
__global__ __launch_bounds__(256)
void mcdc_prep(const float* __restrict__ w3, const float* __restrict__ w5,
               const float* __restrict__ w7, unsigned short* __restrict__ ws)
{
    int idx = blockIdx.x * 256 + threadIdx.x;
    const float* src; int KKv, base;
    if (idx < WS5_BASE)      { src = w3; KKv = 9;  base = WS3_BASE; }
    else if (idx < WS7_BASE) { src = w5; KKv = 25; base = WS5_BASE; }
    else                     { src = w7; KKv = 49; base = WS7_BASE; }
    int rel = idx - base;
    int e  = rel & 7;
    int l  = (rel >> 3) & 63;
    int gm = (rel >> 9) & 15;
    int ks = rel >> 13;
    int o  = gm * 16 + (l & 15);
    int r  = ks * 32 + (l >> 4) * 8 + e;
    int j  = r >> 8;
    int c  = r & 255;
    ws[idx] = f2bf(src[((size_t)o * CIN + c) * KKv + j]);
}

// ---------------- fused sample + GEMM ----------------
// Block: 256 threads = 4 waves. BM=128 (m-half mb), BN=128 pixels, K-range [ks0,ks1).
// Wave w computes all 128 m-rows x 32 pixels [w*32, w*32+32): mf=8, nf=2.
template<int K, int CH_OFF, int OC_OFF, bool ATOMIC>
__device__ __forceinline__ void dconv(
    const float* __restrict__ feat, const float* __restrict__ off,
    const unsigned short* __restrict__ wsA, float* __restrict__ out,
    int b, int p0, int mb, int ks0, int ks1,
    unsigned short (&sB)[2][128][40], uint4 (&meta)[2][128])
{
    const int tid  = threadIdx.x;
    const int lane = tid & 63;
    const int w    = tid >> 6;          // wave id: pixel slice [w*32, w*32+32)
    const int pxs  = tid & 127;         // staging pixel
    const int half = tid >> 7;          // staging c-half (0: c 0..15, 1: c 16..31 of kstep)

    // bilinear meta for tap jn, all 128 pixels (threads 0..127)
    auto computeMeta = [&](int jn) {
        if (tid < 128) {
            const int p = tid, pix = p0 + p;
            const int y = pix >> 6, x = pix & 63;
            const float* ob = off + ((size_t)(b * OFFC + CH_OFF + 2 * jn)) * HW + (y << 6) + x;
            const float oy = ob[0], ox = ob[HW];
            const float sy = (float)y + oy, sx = (float)x + ox;
            const float fy = floorf(sy), fx = floorf(sx);
            const float dy = sy - fy, dx = sx - fx;
            const int y0 = (int)fy, x0 = (int)fx;
            const int y1 = y0 + 1,  x1 = x0 + 1;
            const bool vy0 = (y0 >= 0) & (y0 < 64), vy1 = (y1 >= 0) & (y1 < 64);
            const bool vx0 = (x0 >= 0) & (x0 < 64), vx1 = (x1 >= 0) & (x1 < 64);
            const float w00 = (1.f - dy) * (1.f - dx) * ((vy0 && vx0) ? 1.f : 0.f);
            const float w01 = (1.f - dy) * dx         * ((vy0 && vx1) ? 1.f : 0.f);
            const float w10 = dy * (1.f - dx)         * ((vy1 && vx0) ? 1.f : 0.f);
            const float w11 = dy * dx                 * ((vy1 && vx1) ? 1.f : 0.f);
            const int y0c = min(max(y0, 0), 63), y1c = min(max(y1, 0), 63);
            const int x0c = min(max(x0, 0), 63), x1c = min(max(x1, 0), 63);
            uint4 mm;
            mm.x = (unsigned)(y0c * 64 + x0c) | ((unsigned)(y0c * 64 + x1c) << 16);
            mm.y = (unsigned)(y1c * 64 + x0c) | ((unsigned)(y1c * 64 + x1c) << 16);
            mm.z = (unsigned)f2bf(w00) | ((unsigned)f2bf(w01) << 16);
            mm.w = (unsigned)f2bf(w10) | ((unsigned)f2bf(w11) << 16);
            meta[jn & 1][p] = mm;
        }
    };

    // stage k-step ks into sB[ks&1]: thread does 16 c-planes of one pixel (one meta).
    // Wave = 64 consecutive pixels, same c-half -> coalesced gathers, conflict-free writes.
    auto stage = [&](int ks) {
        const int j = ks >> 3;
        const uint4 mm = meta[j & 1][pxs];
        const int i00 = mm.x & 0xffff, i01 = mm.x >> 16;
        const int i10 = mm.y & 0xffff, i11 = mm.y >> 16;
        const float w00 = bf2f(mm.z & 0xffff), w01 = bf2f(mm.z >> 16);
        const float w10 = bf2f(mm.w & 0xffff), w11 = bf2f(mm.w >> 16);
        const int cb = (ks & 7) * 32 + half * 16;
        const float* fp = feat + ((size_t)(b * CIN + cb)) * HW;
        bf16x8 sv0, sv1;
#pragma unroll
        for (int e = 0; e < 8; ++e) {
            const float v = w00 * fp[i00] + w01 * fp[i01] + w10 * fp[i10] + w11 * fp[i11];
            sv0[e] = (short)f2bf(v);
            fp += HW;
        }
#pragma unroll
        for (int e = 0; e < 8; ++e) {
            const float v = w00 * fp[i00] + w01 * fp[i01] + w10 * fp[i10] + w11 * fp[i11];
            sv1[e] = (short)f2bf(v);
            fp += HW;
        }
        *(bf16x8*)(&sB[ks & 1][pxs][half * 16])     = sv0;
        *(bf16x8*)(&sB[ks & 1][pxs][half * 16 + 8]) = sv1;
    };

    auto loadA = [&](bf16x8 (&a)[8], int ks) {
#pragma unroll
        for (int mf = 0; mf < 8; ++mf)
            a[mf] = *(const bf16x8*)(wsA + (((size_t)ks * 16 + mb * 8 + mf) * 64 + lane) * 8);
    };

    f32x4 acc[8][2];
#pragma unroll
    for (int i = 0; i < 8; ++i) { acc[i][0] = f32x4{0,0,0,0}; acc[i][1] = f32x4{0,0,0,0}; }

    bf16x8 a_cur[8], a_nxt[8];
    computeMeta(ks0 >> 3);
    __syncthreads();
    stage(ks0);
    loadA(a_cur, ks0);

    for (int ks = ks0; ks < ks1; ++ks) {
        __syncthreads();                          // sB[ks&1] staged; other buffer free
        if (ks + 1 < ks1) { stage(ks + 1); loadA(a_nxt, ks + 1); }
        if ((ks & 7) == 6 && ks + 2 < ks1) computeMeta((ks + 2) >> 3);

        bf16x8 bf[2];
        const int cu = ks & 1;
#pragma unroll
        for (int nf = 0; nf < 2; ++nf)
            bf[nf] = *(const bf16x8*)(&sB[cu][w * 32 + nf * 16 + (lane & 15)][(lane >> 4) * 8]);
#pragma unroll
        for (int mf = 0; mf < 8; ++mf)
#pragma unroll
            for (int nf = 0; nf < 2; ++nf)
                acc[mf][nf] = __builtin_amdgcn_mfma_f32_16x16x32_bf16(
                    a_cur[mf], bf[nf], acc[mf][nf], 0, 0, 0);
#pragma unroll
        for (int mf = 0; mf < 8; ++mf) a_cur[mf] = a_nxt[mf];
    }

    // epilogue: D layout col=lane&15, row=(lane>>4)*4+r
#pragma unroll
    for (int mf = 0; mf < 8; ++mf) {
#pragma unroll
        for (int nf = 0; nf < 2; ++nf) {
#pragma unroll
            for (int r = 0; r < 4; ++r) {
                const int o = OC_OFF + mb * 128 + mf * 16 + (lane >> 4) * 4 + r;
                const int p = p0 + w * 32 + nf * 16 + (lane & 15);
                float* dst = out + ((size_t)(b * 768 + o)) * HW + p;
                if (ATOMIC) atomicAdd(dst, acc[mf][nf][r]);
                else        *dst = acc[mf][nf][r];
            }
        }
    }
}

__global__ __launch_bounds__(256, 3)
void mcdc_main(const float* __restrict__ feat, const float* __restrict__ off,
               const unsigned short* __restrict__ ws, float* __restrict__ out)
{
    __shared__ __attribute__((aligned(16))) unsigned short sB[2][128][40];
    __shared__ uint4 meta[2][128];

    const int bid = blockIdx.x;
    int br, sub;
    if (bid < 384)      { br = 2; sub = bid; }        // k=7: 3 splits x 2 mb x 64 tiles
    else if (bid < 640) { br = 1; sub = bid - 384; }  // k=5: 2 splits
    else                { br = 0; sub = bid - 640; }  // k=3: 1 split
    const int split = sub >> 7;
    const int rem   = sub & 127;
    const int mb    = rem >> 6;
    const int t     = rem & 63;
    const int b     = t >> 5;
    const int p0    = (t & 31) << 7;

    if (br == 2) {
        const int k7s[4] = {0, 136, 264, 392};        // j-aligned splits of 49*8 ksteps
        dconv<7, 68, 512, true>(feat, off, ws + WS7_BASE, out, b, p0, mb,
                                k7s[split], k7s[split + 1], sB, meta);
    } else if (br == 1) {
        const int k5s[3] = {0, 104, 200};             // 25*8 ksteps
        dconv<5, 18, 256, true>(feat, off, ws + WS5_BASE, out, b, p0, mb,
                                k5s[split], k5s[split + 1], sB, meta);
    } else {
        dconv<3, 0, 0, false>(feat, off, ws + WS3_BASE, out, b, p0, mb,
                              0, 72, sB, meta);       // 9*8 ksteps, single split
    }
}

extern "C" void kernel_launch(void* const* d_in, const int* in_sizes, int n_in,
                              void* d_out, int out_size, void* d_ws, size_t ws_size,
                              hipStream_t stream)
{
    const float* feat = (const float*)d_in[0];
    const float* off  = (const float*)d_in[1];
    const float* w3   = (const float*)d_in[2];
    const float* w5   = (const float*)d_in[3];
    const float* w7   = (const float*)d_in[4];
    float* out = (float*)d_out;
    unsigned short* ws = (unsigned short*)d_ws;

    if (ws_size < (size_t)WS_TOTAL * 2) return;   // loud failure (output stays poisoned)

    hipMemsetAsync(d_out, 0, (size_t)out_size * sizeof(float), stream);
    mcdc_prep<<<dim3(WS_TOTAL / 256), dim3(256), 0, stream>>>(w3, w5, w7, ws);
    mcdc_main<<<dim3(768), dim3(256), 0, stream>>>(feat, off, ws, out);
}

// Round 4
// 406.294 us; speedup vs baseline: 2.7426x; 2.7426x over previous
//
#include <hip/hip_runtime.h>

using bf16x8 = __attribute__((ext_vector_type(8))) short;
using f32x4  = __attribute__((ext_vector_type(4))) float;

#define HW   4096
#define CIN  256
#define OFFC 166

// ws layout: [0, WBYTES) bf16 weights fragment-major; then quad/pair feat pack.
#define WS3_BASE 0
#define WS5_BASE 589824
#define WS7_BASE 2228224
#define WS_TOTAL 5439488                 // ushorts
#define WBYTES   (WS_TOTAL * 2)          // 10,878,976 B
#define QELEMS   1048576                 // 2 b * 128 c2 * 4096 pos
#define QBYTES   (QELEMS * 16)           // quad2: 16 MB
#define PBYTES   (QELEMS * 8)            // pair2:  8 MB

__device__ __forceinline__ unsigned short f2bf(float f) {
    unsigned u = __builtin_bit_cast(unsigned, f);
    return (unsigned short)((u + 0x7fffu + ((u >> 16) & 1u)) >> 16);   // RNE
}
__device__ __forceinline__ float bf2f(unsigned v) {
    return __builtin_bit_cast(float, v << 16);
}

// ---------------- weight prep: fp32 [o][c][kh][kw] -> bf16 fragment-major ----------------
// ws[((ks*16+gm)*64+lane)*8+e] = w[o=gm*16+(lane&15)][c][j], r=ks*32+(lane>>4)*8+e, j=r>>8, c=r&255
__global__ __launch_bounds__(256)
void mcdc_prep_w(const float* __restrict__ w3, const float* __restrict__ w5,
                 const float* __restrict__ w7, unsigned short* __restrict__ ws)
{
    int idx = blockIdx.x * 256 + threadIdx.x;
    const float* src; int KKv, base;
    if (idx < WS5_BASE)      { src = w3; KKv = 9;  base = WS3_BASE; }
    else if (idx < WS7_BASE) { src = w5; KKv = 25; base = WS5_BASE; }
    else                     { src = w7; KKv = 49; base = WS7_BASE; }
    int rel = idx - base;
    int e  = rel & 7;
    int l  = (rel >> 3) & 63;
    int gm = (rel >> 9) & 15;
    int ks = rel >> 13;
    int o  = gm * 16 + (l & 15);
    int r  = ks * 32 + (l >> 4) * 8 + e;
    ws[idx] = f2bf(src[((size_t)o * CIN + (r & 255)) * KKv + (r >> 8)]);
}

// ---------------- feat prep: corner-quad, 2 c-planes interleaved (MODE 0) ----------------
// q[(b*128+c2)*4096 + y*64+x] = { c0:{f(y,x),f(y,xp)},{f(yp,x),f(yp,xp)},  c1: same }
__global__ __launch_bounds__(256)
void mcdc_prep_q(const float* __restrict__ feat, uint4* __restrict__ q)
{
    int idx = blockIdx.x * 256 + threadIdx.x;          // [0, QELEMS)
    int b = idx >> 19, c2 = (idx >> 12) & 127, pos = idx & 4095;
    int y = pos >> 6, x = pos & 63;
    int xp = min(x + 1, 63), yp = min(y + 1, 63);
    const float* f0 = feat + ((size_t)(b * CIN + 2 * c2)) * HW;
    const float* f1 = f0 + HW;
    uint4 o;
    o.x = (unsigned)f2bf(f0[y  * 64 + x]) | ((unsigned)f2bf(f0[y  * 64 + xp]) << 16);
    o.y = (unsigned)f2bf(f0[yp * 64 + x]) | ((unsigned)f2bf(f0[yp * 64 + xp]) << 16);
    o.z = (unsigned)f2bf(f1[y  * 64 + x]) | ((unsigned)f2bf(f1[y  * 64 + xp]) << 16);
    o.w = (unsigned)f2bf(f1[yp * 64 + x]) | ((unsigned)f2bf(f1[yp * 64 + xp]) << 16);
    q[idx] = o;
}

// ---------------- feat prep: x-pair only (MODE 1 fallback, half the ws) ----------------
__global__ __launch_bounds__(256)
void mcdc_prep_p(const float* __restrict__ feat, uint2* __restrict__ q)
{
    int idx = blockIdx.x * 256 + threadIdx.x;
    int b = idx >> 19, c2 = (idx >> 12) & 127, pos = idx & 4095;
    int y = pos >> 6, x = pos & 63;
    int xp = min(x + 1, 63);
    const float* f0 = feat + ((size_t)(b * CIN + 2 * c2)) * HW;
    const float* f1 = f0 + HW;
    uint2 o;
    o.x = (unsigned)f2bf(f0[y * 64 + x]) | ((unsigned)f2bf(f0[y * 64 + xp]) << 16);
    o.y = (unsigned)f2bf(f1[y * 64 + x]) | ((unsigned)f2bf(f1[y * 64 + xp]) << 16);
    q[idx] = o;
}

// ---------------- fused sample + GEMM ----------------
// 512 threads = 8 waves. BM=256, BN=64 px, K-range [ks0,ks1).
// Wave: mh=wid&1 (m-half, mf=8), pq=wid>>1 (16-px quarter, nf=1). acc = 8 x f32x4.
template<int K, int CH_OFF, int OC_OFF, bool ATOMIC, int MODE>
__device__ __forceinline__ void dconv(
    const float* __restrict__ feat, const float* __restrict__ off,
    const unsigned short* __restrict__ wsA, const void* __restrict__ qf,
    float* __restrict__ out, int b, int p0, int ks0, int ks1,
    unsigned short (&sB)[2][64][40], uint4 (&meta)[2][64])
{
    const int tid  = threadIdx.x;
    const int lane = tid & 63;
    const int wid  = tid >> 6;
    const int mh   = wid & 1;
    const int pq   = wid >> 1;
    const int pxs  = tid & 63;          // staging pixel
    const int coct = tid >> 6;          // staging c-quad id (4 c each)

    auto computeMeta = [&](int jn) {
        if (tid < 64) {
            const int pix = p0 + tid;
            const int y = pix >> 6, x = pix & 63;
            const float* ob = off + ((size_t)(b * OFFC + CH_OFF + 2 * jn)) * HW + pix;
            const float oy = ob[0], ox = ob[HW];
            const float sy = (float)y + oy, sx = (float)x + ox;
            const float fy = floorf(sy), fx = floorf(sx);
            const float dy = sy - fy, dx = sx - fx;
            const int y0 = (int)fy, x0 = (int)fx;
            const bool vy0 = (y0 >= 0) & (y0 < 64), vy1 = (y0 >= -1) & (y0 < 63);
            const bool vx0 = (x0 >= 0) & (x0 < 64), vx1 = (x0 >= -1) & (x0 < 63);
            const float w00 = (1.f - dy) * (1.f - dx) * ((vy0 && vx0) ? 1.f : 0.f);
            const float w01 = (1.f - dy) * dx         * ((vy0 && vx1) ? 1.f : 0.f);
            const float w10 = dy * (1.f - dx)         * ((vy1 && vx0) ? 1.f : 0.f);
            const float w11 = dy * dx                 * ((vy1 && vx1) ? 1.f : 0.f);
            const int ya  = min(max(y0, 0), 63),     xa  = min(max(x0, 0), 63);
            const int y1c = min(max(y0 + 1, 0), 63), x1c = min(max(x0 + 1, 0), 63);
            uint4 mm;
            mm.x = (unsigned)(ya * 64 + xa) | ((unsigned)(y1c - ya) << 12)
                                            | ((unsigned)(x1c - xa) << 13);
            mm.y = 0;
            mm.z = (unsigned)f2bf(w00) | ((unsigned)f2bf(w01) << 16);
            mm.w = (unsigned)f2bf(w10) | ((unsigned)f2bf(w11) << 16);
            meta[jn & 1][tid] = mm;
        }
    };

    // stage kstep ks: thread covers 4 c-planes (cb..cb+3) of pixel pxs.
    auto stage = [&](int ks) {
        const int j = ks >> 3;
        const uint4 mm = meta[j & 1][pxs];
        const int  base = mm.x & 4095;
        const unsigned sy1 = (mm.x >> 12) & 1, sx1 = (mm.x >> 13) & 1;
        const float w00 = bf2f(mm.z & 0xffff), w01 = bf2f(mm.z >> 16);
        const float w10 = bf2f(mm.w & 0xffff), w11 = bf2f(mm.w >> 16);
        unsigned short s[4];
        if (MODE == 0) {
            const int c2 = (ks & 7) * 16 + coct * 2;
            const uint4* qp = (const uint4*)qf + (((size_t)(b * 128 + c2)) << 12) + base;
            const uint4 g0 = qp[0];
            const uint4 g1 = qp[1 << 12];
#pragma unroll
            for (int i = 0; i < 2; ++i) {
                const uint4 g = i ? g1 : g0;
                {   // even c: top=g.x, bottom=g.y
                    const unsigned db = sy1 ? g.y : g.x;
                    const float v00 = bf2f(g.x & 0xffff);
                    const float v01 = sx1 ? bf2f(g.x >> 16) : v00;
                    const float v10 = bf2f(db & 0xffff);
                    const float v11 = sx1 ? bf2f(db >> 16) : v10;
                    s[i * 2] = f2bf(w00 * v00 + w01 * v01 + w10 * v10 + w11 * v11);
                }
                {   // odd c: top=g.z, bottom=g.w
                    const unsigned db = sy1 ? g.w : g.z;
                    const float v00 = bf2f(g.z & 0xffff);
                    const float v01 = sx1 ? bf2f(g.z >> 16) : v00;
                    const float v10 = bf2f(db & 0xffff);
                    const float v11 = sx1 ? bf2f(db >> 16) : v10;
                    s[i * 2 + 1] = f2bf(w00 * v00 + w01 * v01 + w10 * v10 + w11 * v11);
                }
            }
        } else if (MODE == 1) {
            const int c2 = (ks & 7) * 16 + coct * 2;
#pragma unroll
            for (int i = 0; i < 2; ++i) {
                const uint2* qp = (const uint2*)qf + (((size_t)(b * 128 + c2 + i)) << 12) + base;
                const uint2 gt = qp[0];
                const uint2 gb = qp[sy1 << 6];
                {
                    const float v00 = bf2f(gt.x & 0xffff);
                    const float v01 = sx1 ? bf2f(gt.x >> 16) : v00;
                    const float v10 = bf2f(gb.x & 0xffff);
                    const float v11 = sx1 ? bf2f(gb.x >> 16) : v10;
                    s[i * 2] = f2bf(w00 * v00 + w01 * v01 + w10 * v10 + w11 * v11);
                }
                {
                    const float v00 = bf2f(gt.y & 0xffff);
                    const float v01 = sx1 ? bf2f(gt.y >> 16) : v00;
                    const float v10 = bf2f(gb.y & 0xffff);
                    const float v11 = sx1 ? bf2f(gb.y >> 16) : v10;
                    s[i * 2 + 1] = f2bf(w00 * v00 + w01 * v01 + w10 * v10 + w11 * v11);
                }
            }
        } else {   // MODE 2: direct fp32 gathers (no extra ws)
            const int cb = (ks & 7) * 32 + coct * 4;
            const int dyo = (int)(sy1 << 6);
#pragma unroll
            for (int e = 0; e < 4; ++e) {
                const float* fp = feat + ((size_t)(b * CIN + cb + e)) * HW + base;
                const float v00 = fp[0], v01 = fp[sx1];
                const float v10 = fp[dyo], v11 = fp[dyo + sx1];
                s[e] = f2bf(w00 * v00 + w01 * v01 + w10 * v10 + w11 * v11);
            }
        }
        uint2 wv;
        wv.x = (unsigned)s[0] | ((unsigned)s[1] << 16);
        wv.y = (unsigned)s[2] | ((unsigned)s[3] << 16);
        *(uint2*)(&sB[ks & 1][pxs][coct * 4]) = wv;
    };

    f32x4 acc[8];
#pragma unroll
    for (int i = 0; i < 8; ++i) acc[i] = f32x4{0.f, 0.f, 0.f, 0.f};

    computeMeta(ks0 >> 3);
    __syncthreads();
    stage(ks0);

    for (int ks = ks0; ks < ks1; ++ks) {
        __syncthreads();                         // sB[ks&1] ready; other buffer free
        if (ks + 1 < ks1) stage(ks + 1);         // issue gathers early, overlap MFMA
        if ((ks & 7) == 6 && ks + 2 < ks1) computeMeta((ks + 2) >> 3);

        const bf16x8 bfr = *(const bf16x8*)(&sB[ks & 1][pq * 16 + (lane & 15)][(lane >> 4) * 8]);
#pragma unroll
        for (int g = 0; g < 2; ++g) {            // A in 2 groups of 4 (VGPR pressure)
            bf16x8 a[4];
#pragma unroll
            for (int mf = 0; mf < 4; ++mf)
                a[mf] = *(const bf16x8*)(wsA +
                    (((size_t)ks * 16 + mh * 8 + g * 4 + mf) * 64 + lane) * 8);
#pragma unroll
            for (int mf = 0; mf < 4; ++mf)
                acc[g * 4 + mf] = __builtin_amdgcn_mfma_f32_16x16x32_bf16(
                    a[mf], bfr, acc[g * 4 + mf], 0, 0, 0);
        }
    }

    // epilogue: D layout col=lane&15, row=(lane>>4)*4+r
#pragma unroll
    for (int mf = 0; mf < 8; ++mf) {
#pragma unroll
        for (int r = 0; r < 4; ++r) {
            const int o = OC_OFF + mh * 128 + mf * 16 + (lane >> 4) * 4 + r;
            const int p = p0 + pq * 16 + (lane & 15);
            float* dst = out + ((size_t)(b * 768 + o)) * HW + p;
            if (ATOMIC) atomicAdd(dst, acc[mf][r]);
            else        *dst = acc[mf][r];
        }
    }
}

// bid -> (xcd, tile, role): XCD-pinned contiguous px-tiles; role-major within XCD so
// weight slices stay L2-resident. 1408 = 8 xcd * 16 tiles * 11 roles.
template<int MODE>
__global__ __launch_bounds__(512, 4)
void mcdc_main(const float* __restrict__ feat, const float* __restrict__ off,
               const unsigned short* __restrict__ ws, const void* __restrict__ qf,
               float* __restrict__ out)
{
    __shared__ __attribute__((aligned(16))) unsigned short sB[2][64][40];
    __shared__ uint4 meta[2][64];

    const int bid  = blockIdx.x;
    const int xcd  = bid & 7;
    const int k    = bid >> 3;          // 0..175
    const int tl   = k & 15;
    const int role = k >> 4;            // 0..10
    const int tile = xcd * 16 + tl;     // 0..127
    const int b    = tile >> 6;
    const int p0   = (tile & 63) << 6;

    if (role < 6) {           // k=7: 392 ksteps in 6 splits {64,...,64,72}
        const int ks0 = role * 64;
        const int ks1 = (role == 5) ? 392 : ks0 + 64;
        dconv<7, 68, 512, true, MODE>(feat, off, ws + WS7_BASE, qf, out, b, p0, ks0, ks1, sB, meta);
    } else if (role < 10) {   // k=5: 200 ksteps in 4 splits {48,48,48,56}
        const int r = role - 6;
        const int ks0 = r * 48;
        const int ks1 = (r == 3) ? 200 : ks0 + 48;
        dconv<5, 18, 256, true, MODE>(feat, off, ws + WS5_BASE, qf, out, b, p0, ks0, ks1, sB, meta);
    } else {                  // k=3: 72 ksteps, no split, plain store
        dconv<3, 0, 0, false, MODE>(feat, off, ws + WS3_BASE, qf, out, b, p0, 0, 72, sB, meta);
    }
}

extern "C" void kernel_launch(void* const* d_in, const int* in_sizes, int n_in,
                              void* d_out, int out_size, void* d_ws, size_t ws_size,
                              hipStream_t stream)
{
    const float* feat = (const float*)d_in[0];
    const float* off  = (const float*)d_in[1];
    const float* w3   = (const float*)d_in[2];
    const float* w5   = (const float*)d_in[3];
    const float* w7   = (const float*)d_in[4];
    float* out = (float*)d_out;
    unsigned short* ws = (unsigned short*)d_ws;
    void* qf = (void*)((char*)d_ws + WBYTES);

    hipMemsetAsync(d_out, 0, (size_t)out_size * sizeof(float), stream);
    mcdc_prep_w<<<dim3(WS_TOTAL / 256), dim3(256), 0, stream>>>(w3, w5, w7, ws);

    if (ws_size >= (size_t)WBYTES + QBYTES) {
        mcdc_prep_q<<<dim3(QELEMS / 256), dim3(256), 0, stream>>>(feat, (uint4*)qf);
        mcdc_main<0><<<dim3(1408), dim3(512), 0, stream>>>(feat, off, ws, qf, out);
    } else if (ws_size >= (size_t)WBYTES + PBYTES) {
        mcdc_prep_p<<<dim3(QELEMS / 256), dim3(256), 0, stream>>>(feat, (uint2*)qf);
        mcdc_main<1><<<dim3(1408), dim3(512), 0, stream>>>(feat, off, ws, qf, out);
    } else {
        mcdc_main<2><<<dim3(1408), dim3(512), 0, stream>>>(feat, off, ws, qf, out);
    }
}

// Round 5
// 374.786 us; speedup vs baseline: 2.9732x; 1.0841x over previous
//
#include <hip/hip_runtime.h>

using bf16x8 = __attribute__((ext_vector_type(8))) short;
using f32x4  = __attribute__((ext_vector_type(4))) float;

#define HW   4096
#define CIN  256
#define OFFC 166

// ws layout: [0, WBYTES) bf16 weights fragment-major; then quad feat pack.
#define WS3_BASE 0
#define WS5_BASE 589824
#define WS7_BASE 2228224
#define WS_TOTAL 5439488                 // ushorts
#define WBYTES   (WS_TOTAL * 2)
#define QELEMS   1048576                 // 2 b * 128 c2 * 4096 pos
#define QBYTES   (QELEMS * 16)           // 16 MB quad pack

__device__ __forceinline__ unsigned short f2bf(float f) {
    unsigned u = __builtin_bit_cast(unsigned, f);
    return (unsigned short)((u + 0x7fffu + ((u >> 16) & 1u)) >> 16);   // RNE
}
__device__ __forceinline__ float bf2f(unsigned v) {
    return __builtin_bit_cast(float, v << 16);
}
__device__ __forceinline__ unsigned cvt_pk_bf16(float lo, float hi) {
    unsigned r;
    asm volatile("v_cvt_pk_bf16_f32 %0, %1, %2" : "=v"(r) : "v"(lo), "v"(hi));
    return r;
}

// ---------------- weight prep: fp32 [o][c][kh][kw] -> bf16 fragment-major ----------------
// ws[((ks*16+gm)*64+lane)*8+e] = w[o=gm*16+(lane&15)][c][j], r=ks*32+(lane>>4)*8+e, j=r>>8, c=r&255
__global__ __launch_bounds__(256)
void mcdc_prep_w(const float* __restrict__ w3, const float* __restrict__ w5,
                 const float* __restrict__ w7, unsigned short* __restrict__ ws)
{
    int idx = blockIdx.x * 256 + threadIdx.x;
    const float* src; int KKv, base;
    if (idx < WS5_BASE)      { src = w3; KKv = 9;  base = WS3_BASE; }
    else if (idx < WS7_BASE) { src = w5; KKv = 25; base = WS5_BASE; }
    else                     { src = w7; KKv = 49; base = WS7_BASE; }
    int rel = idx - base;
    int e  = rel & 7;
    int l  = (rel >> 3) & 63;
    int gm = (rel >> 9) & 15;
    int ks = rel >> 13;
    int o  = gm * 16 + (l & 15);
    int r  = ks * 32 + (l >> 4) * 8 + e;
    ws[idx] = f2bf(src[((size_t)o * CIN + (r & 255)) * KKv + (r >> 8)]);
}

// ---------------- feat prep: corner-quad, 2 c-planes interleaved ----------------
// q[(b*128+c2)*4096 + y*64+x] = { c0:{f(y,x),f(y,xp)},{f(yp,x),f(yp,xp)}, c1: same }
__global__ __launch_bounds__(256)
void mcdc_prep_q(const float* __restrict__ feat, uint4* __restrict__ q)
{
    int idx = blockIdx.x * 256 + threadIdx.x;          // [0, QELEMS)
    int b = idx >> 19, c2 = (idx >> 12) & 127, pos = idx & 4095;
    int y = pos >> 6, x = pos & 63;
    int xp = min(x + 1, 63), yp = min(y + 1, 63);
    const float* f0 = feat + ((size_t)(b * CIN + 2 * c2)) * HW;
    const float* f1 = f0 + HW;
    uint4 o;
    o.x = (unsigned)f2bf(f0[y  * 64 + x]) | ((unsigned)f2bf(f0[y  * 64 + xp]) << 16);
    o.y = (unsigned)f2bf(f0[yp * 64 + x]) | ((unsigned)f2bf(f0[yp * 64 + xp]) << 16);
    o.z = (unsigned)f2bf(f1[y  * 64 + x]) | ((unsigned)f2bf(f1[y  * 64 + xp]) << 16);
    o.w = (unsigned)f2bf(f1[yp * 64 + x]) | ((unsigned)f2bf(f1[yp * 64 + xp]) << 16);
    q[idx] = o;
}

// ---------------- fused sample + GEMM ----------------
// 512 threads = 8 waves. BM=256, BN=64 px, K-range [ks0,ks1).
// Wave: mh=wid&1 (m-half, mf=8), pq=wid>>1 (16-px quarter, nf=1).
// Staging: thread = (pixel pxs, c-quad coct=wid); per-thread reg meta; 2-deep gather pipe.
template<int K, int CH_OFF, int OC_OFF, bool ATOMIC, int MODE>
__device__ __forceinline__ void dconv(
    const float* __restrict__ feat, const float* __restrict__ off,
    const unsigned short* __restrict__ wsA, const uint4* __restrict__ qf,
    float* __restrict__ out, int b, int p0, int ks0, int ks1,
    unsigned short (&sB)[2][64][40])
{
    const int tid  = threadIdx.x;
    const int lane = tid & 63;
    const int wid  = tid >> 6;
    const int mh   = wid & 1;
    const int pq   = wid >> 1;
    const int pxs  = tid & 63;          // staging pixel
    const int coct = wid;               // staging c-quad (4 c-planes)

    const int pix = p0 + pxs, py = pix >> 6, px = pix & 63;

    // per-thread bilinear meta, double-slotted by j&1
    const uint4* qbase[2];
    const float* fbase[2];
    int   fxo[2], fyo[2];
    float mw[2][4];

    auto computeMeta = [&](int j) {
        const int s = j & 1;
        const float* ob = off + ((size_t)(b * OFFC + CH_OFF + 2 * j)) * HW + pix;
        const float oy = ob[0], ox = ob[HW];
        const float sy = (float)py + oy, sx = (float)px + ox;
        const float fy = floorf(sy), fx = floorf(sx);
        const float dy = sy - fy, dx = sx - fx;
        const int y0 = (int)fy, x0 = (int)fx;
        const bool vy0 = (y0 >= 0) & (y0 < 64), vy1 = (y0 >= -1) & (y0 < 63);
        const bool vx0 = (x0 >= 0) & (x0 < 64), vx1 = (x0 >= -1) & (x0 < 63);
        float w00 = (1.f - dy) * (1.f - dx) * ((vy0 && vx0) ? 1.f : 0.f);
        float w01 = (1.f - dy) * dx         * ((vy0 && vx1) ? 1.f : 0.f);
        float w10 = dy * (1.f - dx)         * ((vy1 && vx0) ? 1.f : 0.f);
        float w11 = dy * dx                 * ((vy1 && vx1) ? 1.f : 0.f);
        const int ya  = min(max(y0, 0), 63),     xa  = min(max(x0, 0), 63);
        const int y1c = min(max(y0 + 1, 0), 63), x1c = min(max(x0 + 1, 0), 63);
        // fold degenerate axes into weights -> stage needs no selects
        if (x1c == xa) { w00 += w01; w10 += w11; w01 = 0.f; w11 = 0.f; }
        if (y1c == ya) { w00 += w10; w01 += w11; w10 = 0.f; w11 = 0.f; }
        mw[s][0] = w00; mw[s][1] = w01; mw[s][2] = w10; mw[s][3] = w11;
        const int base = ya * 64 + xa;
        if (MODE == 0) {
            qbase[s] = qf + (((size_t)(b * 128 + coct * 2)) << 12) + base;
        } else {
            fbase[s] = feat + ((size_t)(b * CIN)) * HW + base;
            fxo[s] = x1c - xa; fyo[s] = (y1c - ya) * 64;
        }
    };

    uint4 gA0, gA1, gB0, gB1;            // MODE0 payload
    float fA[16], fB[16];                // MODE2 payload (dead under MODE0)

    auto gissue = [&](int ks, uint4& g0, uint4& g1, float* f) {
        const int s = (ks >> 3) & 1;
        if (MODE == 0) {
            const uint4* qp = qbase[s] + ((ks & 7) << 16);
            g0 = qp[0];
            g1 = qp[4096];
        } else {
            const float* fp = fbase[s] + ((size_t)((ks & 7) * 32 + coct * 4)) * HW;
            const int xo = fxo[s], yo = fyo[s];
#pragma unroll
            for (int e = 0; e < 4; ++e) {
                f[e*4+0] = fp[0]; f[e*4+1] = fp[xo]; f[e*4+2] = fp[yo]; f[e*4+3] = fp[yo+xo];
                fp += HW;
            }
        }
    };

    auto bwrite = [&](int ks, const uint4& g0, const uint4& g1, const float* f) {
        const int s = (ks >> 3) & 1;
        const float w00 = mw[s][0], w01 = mw[s][1], w10 = mw[s][2], w11 = mw[s][3];
        float v[4];
        if (MODE == 0) {
            v[0] = w00*bf2f(g0.x & 0xffff) + w01*bf2f(g0.x >> 16)
                 + w10*bf2f(g0.y & 0xffff) + w11*bf2f(g0.y >> 16);
            v[1] = w00*bf2f(g0.z & 0xffff) + w01*bf2f(g0.z >> 16)
                 + w10*bf2f(g0.w & 0xffff) + w11*bf2f(g0.w >> 16);
            v[2] = w00*bf2f(g1.x & 0xffff) + w01*bf2f(g1.x >> 16)
                 + w10*bf2f(g1.y & 0xffff) + w11*bf2f(g1.y >> 16);
            v[3] = w00*bf2f(g1.z & 0xffff) + w01*bf2f(g1.z >> 16)
                 + w10*bf2f(g1.w & 0xffff) + w11*bf2f(g1.w >> 16);
        } else {
#pragma unroll
            for (int e = 0; e < 4; ++e)
                v[e] = w00*f[e*4] + w01*f[e*4+1] + w10*f[e*4+2] + w11*f[e*4+3];
        }
        uint2 wv;
        wv.x = cvt_pk_bf16(v[0], v[1]);
        wv.y = cvt_pk_bf16(v[2], v[3]);
        *(uint2*)(&sB[ks & 1][pxs][coct * 4]) = wv;
    };

    f32x4 acc[8];
#pragma unroll
    for (int i = 0; i < 8; ++i) acc[i] = f32x4{0.f, 0.f, 0.f, 0.f};

    auto iter = [&](int ks, uint4& gc0, uint4& gc1, float* fc,
                    uint4& gn0, uint4& gn1, float* fn) {
        __syncthreads();                                  // sB[ks&1] staged by all
        if ((ks & 7) == 6 && ks + 2 < ks1) computeMeta((ks + 2) >> 3);
        { const int kg = min(ks + 2, ks1 - 1); gissue(kg, gn0, gn1, fn); }
        const bf16x8 bfr = *(const bf16x8*)(&sB[ks & 1][pq * 16 + (lane & 15)][(lane >> 4) * 8]);
        const unsigned short* ap = wsA + (((size_t)ks * 16 + mh * 8) * 64 + lane) * 8;
        bf16x8 a[8];
#pragma unroll
        for (int mf = 0; mf < 8; ++mf) a[mf] = *(const bf16x8*)(ap + mf * 512);
        if (ks + 1 < ks1) bwrite(ks + 1, gc0, gc1, fc);   // VALU fills A-load shadow
#pragma unroll
        for (int mf = 0; mf < 8; ++mf)
            acc[mf] = __builtin_amdgcn_mfma_f32_16x16x32_bf16(a[mf], bfr, acc[mf], 0, 0, 0);
    };

    // prologue: meta, gathers for ks0 and ks0+1, stage ks0
    computeMeta(ks0 >> 3);
    gissue(ks0, gA0, gA1, fA);
    gissue(min(ks0 + 1, ks1 - 1), gB0, gB1, fB);
    bwrite(ks0, gA0, gA1, fA);

    for (int ks = ks0; ks < ks1; ks += 2) {               // all splits even-length
        iter(ks,     gB0, gB1, fB, gA0, gA1, fA);
        iter(ks + 1, gA0, gA1, fA, gB0, gB1, fB);
    }

    // epilogue: D layout col=lane&15, row=(lane>>4)*4+r
#pragma unroll
    for (int mf = 0; mf < 8; ++mf) {
#pragma unroll
        for (int r = 0; r < 4; ++r) {
            const int o = OC_OFF + mh * 128 + mf * 16 + (lane >> 4) * 4 + r;
            const int p = p0 + pq * 16 + (lane & 15);
            float* dst = out + ((size_t)(b * 768 + o)) * HW + p;
            if (ATOMIC) atomicAdd(dst, acc[mf][r]);
            else        *dst = acc[mf][r];
        }
    }
}

// 1536 = 8 xcd * 16 tiles * 12 roles. XCD-pinned; role 0 (k3, longest) dispatched first.
template<int MODE>
__global__ __launch_bounds__(512, 4)
void mcdc_main(const float* __restrict__ feat, const float* __restrict__ off,
               const unsigned short* __restrict__ ws, const uint4* __restrict__ qf,
               float* __restrict__ out)
{
    __shared__ __attribute__((aligned(16))) unsigned short sB[2][64][40];

    const int bid  = blockIdx.x;
    const int xcd  = bid & 7;
    const int tl   = (bid >> 3) & 15;
    const int role = bid >> 7;              // 0..11
    const int tile = xcd * 16 + tl;         // 0..127 (xcd 0-3 -> b0, 4-7 -> b1)
    const int b    = tile >> 6;
    const int p0   = (tile & 63) << 6;

    if (role == 0) {                        // k=3: 72 ksteps, whole, plain store
        dconv<3, 0, 0, false, MODE>(feat, off, ws + WS3_BASE, qf, out, b, p0, 0, 72, sB);
    } else if (role <= 7) {                 // k=7: 7 splits of 56
        const int r = role - 1;
        dconv<7, 68, 512, true, MODE>(feat, off, ws + WS7_BASE, qf, out, b, p0,
                                      r * 56, r * 56 + 56, sB);
    } else {                                // k=5: 200 = 48+48+48+56
        const int r = role - 8;
        const int ks0 = r * 48;
        const int ks1 = (r == 3) ? 200 : ks0 + 48;
        dconv<5, 18, 256, true, MODE>(feat, off, ws + WS5_BASE, qf, out, b, p0,
                                      ks0, ks1, sB);
    }
}

extern "C" void kernel_launch(void* const* d_in, const int* in_sizes, int n_in,
                              void* d_out, int out_size, void* d_ws, size_t ws_size,
                              hipStream_t stream)
{
    const float* feat = (const float*)d_in[0];
    const float* off  = (const float*)d_in[1];
    const float* w3   = (const float*)d_in[2];
    const float* w5   = (const float*)d_in[3];
    const float* w7   = (const float*)d_in[4];
    float* out = (float*)d_out;
    unsigned short* ws = (unsigned short*)d_ws;
    uint4* qf = (uint4*)((char*)d_ws + WBYTES);

    hipMemsetAsync(d_out, 0, (size_t)out_size * sizeof(float), stream);
    mcdc_prep_w<<<dim3(WS_TOTAL / 256), dim3(256), 0, stream>>>(w3, w5, w7, ws);

    if (ws_size >= (size_t)WBYTES + QBYTES) {
        mcdc_prep_q<<<dim3(QELEMS / 256), dim3(256), 0, stream>>>(feat, qf);
        mcdc_main<0><<<dim3(1536), dim3(512), 0, stream>>>(feat, off, ws, qf, out);
    } else {
        mcdc_main<2><<<dim3(1536), dim3(512), 0, stream>>>(feat, off, ws, nullptr, out);
    }
}